// Round 16
// baseline (801.795 us; speedup 1.0000x reference)
//
#include <hip/hip_runtime.h>

typedef unsigned short u16;
typedef u16  u16x8 __attribute__((ext_vector_type(8)));
typedef u16  u16x4 __attribute__((ext_vector_type(4)));
typedef short s16x8 __attribute__((ext_vector_type(8)));
typedef float f32x4 __attribute__((ext_vector_type(4)));

static constexpr int TT   = 2048;   // tokens (B*S)
static constexpr int HD   = 2048;   // hidden
static constexpr int ID   = 1408;   // expert intermediate
static constexpr int NE   = 16;     // experts
static constexpr int TOPK = 6;
static constexpr int CAPE = 1536;   // capacity
static constexpr int SHD  = 2816;   // shared intermediate (2*I)
static constexpr float RSF_ = 2.5f;
static constexpr int PGRID = 1024;  // persistent blocks (256 CU x 4)

struct PJob {               // one dual-GEMM job: act = silu(A*B0^T)*(A*B1^T)
  const u16 *B0, *B1;
  u16* C;
  const int* row_map;
  const int* counts;
  int Mfixed, ldc, row_cap, mtiles, ntiles, nexp;
  long b_stride;
};

struct DJob {               // one single-GEMM job for the merged down pass
  const u16* A;
  const u16* Bt;
  void* C;
  const int* counts;
  int Mfixed, K, lda, ldc, row_cap, epi;   // epi: 0=bf16, 1=fp32
  long b_stride;
};

__device__ __forceinline__ u16 f2b(float f) {
  unsigned int u = __builtin_bit_cast(unsigned int, f);
  unsigned int r = (u + 0x7FFFu + ((u >> 16) & 1u)) >> 16;
  return (u16)r;
}
__device__ __forceinline__ float b2f(u16 u) {
  unsigned int v = ((unsigned int)u) << 16;
  return __builtin_bit_cast(float, v);
}

__device__ __forceinline__ void gl_lds16(const u16* gp, u16* lp) {
  __builtin_amdgcn_global_load_lds(
      (const __attribute__((address_space(1))) void*)(unsigned long long)(const void*)gp,
      (__attribute__((address_space(3))) void*)(unsigned int)(unsigned long long)(void*)lp,
      16, 0, 0);
}

// sequential tile order for persistent kernels (bx fastest)
__device__ __forceinline__ void seq_map(int idx, int mtiles, int ntiles,
                                        int& bx, int& by, int& e) {
  bx = idx % mtiles;
  int tq = idx / mtiles;
  by = tq % ntiles;
  e  = tq / ntiles;
}

// ---------------- x fp32 -> bf16 ----------------
__global__ __launch_bounds__(256) void k_cvt(const float* __restrict__ in, u16* __restrict__ out) {
  size_t i = (size_t)blockIdx.x * 256 + threadIdx.x;
  const float4* p = (const float4*)in;
  float4 v0 = p[i * 2], v1 = p[i * 2 + 1];
  u16x8 o = { f2b(v0.x), f2b(v0.y), f2b(v0.z), f2b(v0.w),
              f2b(v1.x), f2b(v1.y), f2b(v1.z), f2b(v1.w) };
  *(u16x8*)(out + i * 8) = o;
}

__global__ __launch_bounds__(64) void k_init(int* c) {
  if (threadIdx.x < 16) c[threadIdx.x] = 0;
}

// ---------------- fused gate ----------------
__global__ __launch_bounds__(256) void k_gate2(const float* __restrict__ x,
    const float* __restrict__ gw, const float* __restrict__ gb,
    int* __restrict__ topk_idx, float* __restrict__ topk_w) {
  const int t = threadIdx.x;
  const int tok0 = blockIdx.x * 8;
  const int i  = t >> 5;
  const int sub = t & 31;
  const int e  = sub & 15;
  const int kh = sub >> 4;
  const float4* xr = (const float4*)(x + (size_t)(tok0 + i) * HD) + kh * (HD / 8);
  const float4* wr = (const float4*)(gw + (size_t)e * HD) + kh * (HD / 8);
  float acc = 0.f;
  #pragma unroll 8
  for (int k = 0; k < HD / 8; ++k) {
    float4 a = xr[k], b = wr[k];
    acc += a.x * b.x + a.y * b.y;
    acc += a.z * b.z + a.w * b.w;
  }
  acc += __shfl_down(acc, 16);
  __shared__ float lg[8][16];
  if (sub < 16) lg[i][e] = acc;
  __syncthreads();
  if (t >= 8) return;
  const int tok = tok0 + t;
  float s[NE], sc[NE];
  #pragma unroll
  for (int ee = 0; ee < NE; ++ee) {
    s[ee]  = 1.f / (1.f + expf(-lg[t][ee]));
    sc[ee] = s[ee] + gb[ee];
  }
  float gs[4];
  #pragma unroll
  for (int g = 0; g < 4; ++g) {
    float m1 = -1e30f, m2 = -1e30f;
    #pragma unroll
    for (int j = 0; j < 4; ++j) {
      float v = sc[g * 4 + j];
      if (v > m1) { m2 = m1; m1 = v; } else if (v > m2) m2 = v;
    }
    gs[g] = m1 + m2;
  }
  int g0 = 0;
  #pragma unroll
  for (int g = 1; g < 4; ++g) if (gs[g] > gs[g0]) g0 = g;
  int g1 = -1; float g1v = -1e30f;
  #pragma unroll
  for (int g = 0; g < 4; ++g) {
    if (g == g0) continue;
    if (g1 < 0 || gs[g] > g1v) { g1 = g; g1v = gs[g]; }
  }
  float tmp[NE];
  #pragma unroll
  for (int ee = 0; ee < NE; ++ee) {
    int g = ee >> 2;
    tmp[ee] = (g == g0 || g == g1) ? sc[ee] : 0.0f;
  }
  unsigned used = 0;
  float wsum = 0.f;
  int idxs[TOPK]; float wv[TOPK];
  #pragma unroll
  for (int k = 0; k < TOPK; ++k) {
    int best = -1; float bv = -2e30f;
    #pragma unroll
    for (int ee = 0; ee < NE; ++ee) {
      bool ok = (((used >> ee) & 1u) == 0u) && (tmp[ee] > bv);
      if (ok) { bv = tmp[ee]; best = ee; }
    }
    used |= 1u << best;
    float sv = 0.f;
    #pragma unroll
    for (int ee = 0; ee < NE; ++ee) if (ee == best) sv = s[ee];
    idxs[k] = best; wv[k] = sv; wsum += sv;
  }
  float scale = RSF_ / (wsum + 1e-20f);
  #pragma unroll
  for (int k = 0; k < TOPK; ++k) {
    topk_idx[tok * TOPK + k] = idxs[k];
    topk_w[tok * TOPK + k]   = wv[k] * scale;
  }
}

// ---------------- stable per-expert positions ----------------
__global__ __launch_bounds__(256) void k_count_pos(const int* __restrict__ topk_idx,
    int* __restrict__ rowidx, int* __restrict__ tok_of_row, int* __restrict__ counts) {
  const int e = blockIdx.x, t = threadIdx.x;
  __shared__ int pref[256];
  const int t0 = t * 8;
  int c = 0;
  for (int tt = t0; tt < t0 + 8; ++tt)
    for (int k = 0; k < TOPK; ++k) c += (topk_idx[tt * TOPK + k] == e) ? 1 : 0;
  pref[t] = c;
  __syncthreads();
  for (int off = 1; off < 256; off <<= 1) {
    int v = (t >= off) ? pref[t - off] : 0;
    __syncthreads();
    pref[t] += v;
    __syncthreads();
  }
  int run = pref[t] - c;
  if (t == 255) counts[e] = (pref[255] < CAPE) ? pref[255] : CAPE;
  for (int tt = t0; tt < t0 + 8; ++tt)
    for (int k = 0; k < TOPK; ++k)
      if (topk_idx[tt * TOPK + k] == e) {
        if (run < CAPE) {
          rowidx[tt * TOPK + k] = e * CAPE + run;
          tok_of_row[e * CAPE + run] = tt;
        } else {
          rowidx[tt * TOPK + k] = -1;
        }
        ++run;
      }
}

// ---------------- transpose + convert: fp32 [R][C] -> bf16 [C][R] ----------------
__global__ __launch_bounds__(256) void k_transpose_cvt(const float* __restrict__ in,
    u16* __restrict__ out, int R, int Cc, long zin, long zout) {
  __shared__ float tile[64][65];
  const float* src = in + (size_t)blockIdx.z * zin;
  u16* dst = out + (size_t)blockIdx.z * zout;
  const int r0 = blockIdx.x * 64, c0 = blockIdx.y * 64, t = threadIdx.x;
  #pragma unroll
  for (int i = 0; i < 4; ++i) {
    int c = t + 256 * i;
    int r = c >> 4, cg = (c & 15) << 2;
    float4 v = *(const float4*)(src + (size_t)(r0 + r) * Cc + c0 + cg);
    tile[r][cg + 0] = v.x; tile[r][cg + 1] = v.y;
    tile[r][cg + 2] = v.z; tile[r][cg + 3] = v.w;
  }
  __syncthreads();
  #pragma unroll
  for (int i = 0; i < 4; ++i) {
    int c = t + 256 * i;
    int oc = c >> 4, og = (c & 15) << 2;
    u16x4 w;
    #pragma unroll
    for (int j = 0; j < 4; ++j) w[j] = f2b(tile[og + j][oc]);
    *(u16x4*)(dst + (size_t)(c0 + oc) * R + r0 + og) = w;
  }
}

// ---- paired transpose: two same-shape matrices in one launch (z split) ----
__global__ __launch_bounds__(256) void k_transpose_cvt2(
    const float* __restrict__ in0, const float* __restrict__ in1,
    u16* __restrict__ out0, u16* __restrict__ out1,
    int R, int Cc, long zin, long zout, int nz) {
  __shared__ float tile[64][65];
  const int zi = blockIdx.z;
  const int mat = (zi >= nz) ? 1 : 0;
  const int zz  = mat ? zi - nz : zi;
  const float* src = (mat ? in1 : in0) + (size_t)zz * zin;
  u16* dst = (mat ? out1 : out0) + (size_t)zz * zout;
  const int r0 = blockIdx.x * 64, c0 = blockIdx.y * 64, t = threadIdx.x;
  #pragma unroll
  for (int i = 0; i < 4; ++i) {
    int c = t + 256 * i;
    int r = c >> 4, cg = (c & 15) << 2;
    float4 v = *(const float4*)(src + (size_t)(r0 + r) * Cc + c0 + cg);
    tile[r][cg + 0] = v.x; tile[r][cg + 1] = v.y;
    tile[r][cg + 2] = v.z; tile[r][cg + 3] = v.w;
  }
  __syncthreads();
  #pragma unroll
  for (int i = 0; i < 4; ++i) {
    int c = t + 256 * i;
    int oc = c >> 4, og = (c & 15) << 2;
    u16x4 w;
    #pragma unroll
    for (int j = 0; j < 4; ++j) w[j] = f2b(tile[og + j][oc]);
    *(u16x4*)(dst + (size_t)(c0 + oc) * R + r0 + og) = w;
  }
}

// ====== merged persistent dual GEMM (2 jobs, one counter) ======
__global__ __launch_bounds__(256, 4) void k_pdual2(
    const u16* __restrict__ A, int K, int lda,
    PJob j1, PJob j2, int* __restrict__ counter) {
  const int t = threadIdx.x;
  const int l = t & 63, w = t >> 6;
  const int wm = (w >> 1) * 64, wn = (w & 1) * 32;
  const int l15 = l & 15, g0 = l >> 4;

  __shared__ __align__(16) u16 As[2][128 * 32];
  __shared__ __align__(16) u16 B0s[2][64 * 32];
  __shared__ __align__(16) u16 B1s[2][64 * 32];
  __shared__ int s_tile;

  int aoff[4], boff[2];
  #pragma unroll
  for (int i = 0; i < 4; ++i) {
    int rA = wm + i * 16 + l15;
    aoff[i] = rA * 64 + ((g0 ^ ((rA >> 1) & 3)) << 4);
  }
  #pragma unroll
  for (int i = 0; i < 2; ++i) {
    int rB = wn + i * 16 + l15;
    boff[i] = rB * 64 + ((g0 ^ ((rB >> 1) & 3)) << 4);
  }

  const int ntot1 = j1.mtiles * j1.ntiles * j1.nexp;
  const int ntot2 = j2.mtiles * j2.ntiles * j2.nexp;
  const int ntot  = ntot1 + ntot2;
  const int nk = K >> 5;
  const int cl = l15, rw = g0 * 4;

  for (;;) {
    if (t == 0) s_tile = atomicAdd(counter, 1);
    __syncthreads();
    int idx = s_tile;
    __syncthreads();
    if (idx >= ntot) break;
    const PJob& J = (idx < ntot1) ? j1 : j2;
    int ii = (idx < ntot1) ? idx : idx - ntot1;
    int bx, by, e;
    seq_map(ii, J.mtiles, J.ntiles, bx, by, e);
    const int cnt = J.counts ? J.counts[e] : J.Mfixed;
    const int M_e = J.counts ? (cnt < J.row_cap ? cnt : J.row_cap) : J.Mfixed;
    const int m0 = bx * 128;
    if (m0 >= M_e) continue;
    const int n0 = by * 64;
    const int row_base = J.counts ? e * J.row_cap : 0;
    const u16* B0e = J.B0 + (size_t)e * J.b_stride;
    const u16* B1e = J.B1 + (size_t)e * J.b_stride;

    const u16 *ap[2], *b0p, *b1p;
    int loffA[2], loffB;
    #pragma unroll
    for (int i = 0; i < 2; ++i) {
      int c = t + 256 * i;
      int row = c >> 2, g = c & 3;
      int kg = g ^ ((row >> 1) & 3);
      loffA[i] = c * 8;
      int rg = m0 + row; if (rg > M_e - 1) rg = M_e - 1;
      int arow = J.row_map ? J.row_map[row_base + rg] : row_base + rg;
      ap[i] = A + (size_t)arow * lda + kg * 8;
    }
    {
      int row = t >> 2, g = t & 3;
      int kg = g ^ ((row >> 1) & 3);
      loffB = t * 8;
      b0p = B0e + (size_t)(n0 + row) * K + kg * 8;
      b1p = B1e + (size_t)(n0 + row) * K + kg * 8;
    }

    f32x4 accg[4][2], accu[4][2];
    #pragma unroll
    for (int m = 0; m < 4; ++m)
      #pragma unroll
      for (int n = 0; n < 2; ++n) { accg[m][n] = f32x4{0,0,0,0}; accu[m][n] = f32x4{0,0,0,0}; }

    #pragma unroll
    for (int i = 0; i < 2; ++i) { gl_lds16(ap[i], &As[0][loffA[i]]); ap[i] += 32; }
    gl_lds16(b0p, &B0s[0][loffB]); b0p += 32;
    gl_lds16(b1p, &B1s[0][loffB]); b1p += 32;
    __syncthreads();
    int cur = 0;
    for (int ks = 0; ks < nk; ++ks) {
      if (ks + 1 < nk) {
        #pragma unroll
        for (int i = 0; i < 2; ++i) { gl_lds16(ap[i], &As[cur ^ 1][loffA[i]]); ap[i] += 32; }
        gl_lds16(b0p, &B0s[cur ^ 1][loffB]); b0p += 32;
        gl_lds16(b1p, &B1s[cur ^ 1][loffB]); b1p += 32;
      }
      s16x8 af[4], bf0[2], bf1[2];
      #pragma unroll
      for (int i = 0; i < 4; ++i)
        af[i] = __builtin_bit_cast(s16x8, *(const u16x8*)((const char*)As[cur] + aoff[i]));
      #pragma unroll
      for (int i = 0; i < 2; ++i) {
        bf0[i] = __builtin_bit_cast(s16x8, *(const u16x8*)((const char*)B0s[cur] + boff[i]));
        bf1[i] = __builtin_bit_cast(s16x8, *(const u16x8*)((const char*)B1s[cur] + boff[i]));
      }
      #pragma unroll
      for (int m = 0; m < 4; ++m)
        #pragma unroll
        for (int n = 0; n < 2; ++n) {
          accg[m][n] = __builtin_amdgcn_mfma_f32_16x16x32_bf16(af[m], bf0[n], accg[m][n], 0, 0, 0);
          accu[m][n] = __builtin_amdgcn_mfma_f32_16x16x32_bf16(af[m], bf1[n], accu[m][n], 0, 0, 0);
        }
      __syncthreads();
      cur ^= 1;
    }

    #pragma unroll
    for (int m = 0; m < 4; ++m) {
      #pragma unroll
      for (int n = 0; n < 2; ++n) {
        f32x4 vg = accg[m][n], vu = accu[m][n];
        int gr0 = m0 + wm + m * 16 + rw;
        int gc  = n0 + wn + n * 16 + cl;
        #pragma unroll
        for (int j = 0; j < 4; ++j) {
          int rr = gr0 + j;
          if (rr < M_e) {
            float gf = vg[j];
            float act = gf / (1.f + __expf(-gf)) * vu[j];
            J.C[(size_t)(row_base + rr) * J.ldc + gc] = f2b(act);
          }
        }
      }
    }
  }
}

// ====== merged single GEMM (2 jobs, one static grid): BM=BN=128, BK=64 ======
// z < nz1 -> job1 expert z; else job2 (expert bz-nz1). Runtime epilogue select.
__global__ __launch_bounds__(256) void k_gemm3m(DJob j1, DJob j2, int nz1) {
  unsigned gx = gridDim.x, gy = gridDim.y, gz = gridDim.z;
  unsigned F = (blockIdx.z * gy + blockIdx.y) * gx + blockIdx.x;
  unsigned Nn = gx * gy * gz;
  unsigned q = Nn >> 3, r = Nn & 7;
  unsigned xcd = F & 7, pos = F >> 3;
  unsigned wi = (xcd < r) ? xcd * (q + 1) + pos
                          : r * (q + 1) + (xcd - r) * q + pos;
  unsigned bx = wi % gx, tq = wi / gx;
  unsigned by = tq % gy, bz = tq / gy;

  const DJob& J = ((int)bz < nz1) ? j1 : j2;
  const int e = ((int)bz < nz1) ? (int)bz : (int)bz - nz1;
  const int K = J.K;
  const int cnt = J.counts ? J.counts[e] : J.Mfixed;
  const int M_e = J.counts ? (cnt < J.row_cap ? cnt : J.row_cap) : J.Mfixed;
  const int m0 = bx * 128;
  if (m0 >= M_e) return;
  const int n0 = by * 128;
  const int row_base = J.counts ? e * J.row_cap : 0;
  const u16* Bte = J.Bt + (size_t)e * J.b_stride;

  __shared__ __align__(16) u16 As[2][128 * 64];   // 16 KB x2
  __shared__ __align__(16) u16 Bs[2][128 * 64];   // 16 KB x2

  const int t = threadIdx.x;
  const int l = t & 63, w = t >> 6;
  const int wm = (w >> 1) * 64, wn = (w & 1) * 64;

  const u16 *ap[4], *bp[4];
  int loff[4];
  #pragma unroll
  for (int i = 0; i < 4; ++i) {
    int c = t + 256 * i;
    int row = c >> 3, pphys = c & 7;
    int kc = pphys ^ (row & 7);
    loff[i] = c * 8;
    int rg = m0 + row; if (rg > M_e - 1) rg = M_e - 1;
    ap[i] = J.A + (size_t)(row_base + rg) * J.lda + kc * 8;
    bp[i] = Bte + (size_t)(n0 + row) * K + kc * 8;
  }

  f32x4 acc[4][4];
  #pragma unroll
  for (int m = 0; m < 4; ++m)
    #pragma unroll
    for (int n = 0; n < 4; ++n) acc[m][n] = f32x4{0, 0, 0, 0};

  const int l15 = l & 15, g0 = l >> 4;
  int aoff[2][4], boff[2][4];
  #pragma unroll
  for (int s = 0; s < 2; ++s)
    #pragma unroll
    for (int i = 0; i < 4; ++i) {
      int rA = wm + i * 16 + l15;
      int rB = wn + i * 16 + l15;
      aoff[s][i] = rA * 128 + ((((s << 2) | g0) ^ (rA & 7)) << 4);
      boff[s][i] = rB * 128 + ((((s << 2) | g0) ^ (rB & 7)) << 4);
    }

  const int nk = K >> 6;
  #pragma unroll
  for (int i = 0; i < 4; ++i) {
    gl_lds16(ap[i], &As[0][loff[i]]); ap[i] += 64;
    gl_lds16(bp[i], &Bs[0][loff[i]]); bp[i] += 64;
  }
  __syncthreads();
  int cur = 0;
  for (int ks = 0; ks < nk; ++ks) {
    if (ks + 1 < nk) {
      #pragma unroll
      for (int i = 0; i < 4; ++i) {
        gl_lds16(ap[i], &As[cur ^ 1][loff[i]]); ap[i] += 64;
        gl_lds16(bp[i], &Bs[cur ^ 1][loff[i]]); bp[i] += 64;
      }
    }
    #pragma unroll
    for (int s = 0; s < 2; ++s) {
      s16x8 af[4], bfr[4];
      #pragma unroll
      for (int i = 0; i < 4; ++i) {
        af[i]  = __builtin_bit_cast(s16x8, *(const u16x8*)((const char*)As[cur] + aoff[s][i]));
        bfr[i] = __builtin_bit_cast(s16x8, *(const u16x8*)((const char*)Bs[cur] + boff[s][i]));
      }
      #pragma unroll
      for (int m = 0; m < 4; ++m)
        #pragma unroll
        for (int n = 0; n < 4; ++n)
          acc[m][n] = __builtin_amdgcn_mfma_f32_16x16x32_bf16(af[m], bfr[n], acc[m][n], 0, 0, 0);
    }
    __syncthreads();
    cur ^= 1;
  }

  const int cl = l15, rw = g0 * 4;
  #pragma unroll
  for (int m = 0; m < 4; ++m) {
    #pragma unroll
    for (int n = 0; n < 4; ++n) {
      f32x4 v = acc[m][n];
      int gr0 = m0 + wm + m * 16 + rw;
      int gc  = n0 + wn + n * 16 + cl;
      #pragma unroll
      for (int j = 0; j < 4; ++j) {
        int rr = gr0 + j;
        if (rr < M_e) {
          size_t ci = (size_t)(row_base + rr) * J.ldc + gc;
          if (J.epi) ((float*)J.C)[ci] = v[j];
          else       ((u16*)J.C)[ci]   = f2b(v[j]);
        }
      }
    }
  }
}

// ---------------- combine ----------------
__global__ __launch_bounds__(256) void k_combine(const u16* __restrict__ down,
    const int* __restrict__ rowidx, const float* __restrict__ tw,
    float* __restrict__ out) {
  const int t = blockIdx.x, l = threadIdx.x;
  __shared__ int rid[TOPK];
  __shared__ float wk[TOPK];
  if (l < TOPK) { rid[l] = rowidx[t * TOPK + l]; wk[l] = tw[t * TOPK + l]; }
  __syncthreads();
  const int h0 = l * 8;
  float* op = out + (size_t)t * HD + h0;
  float4 o0 = *(float4*)op, o1 = *(float4*)(op + 4);
  float a[8] = { o0.x, o0.y, o0.z, o0.w, o1.x, o1.y, o1.z, o1.w };
  #pragma unroll
  for (int k = 0; k < TOPK; ++k) {
    int r = rid[k];
    if (r < 0) continue;
    float wkk = wk[k];
    u16x8 v = *(const u16x8*)(down + (size_t)r * HD + h0);
    #pragma unroll
    for (int j = 0; j < 8; ++j) a[j] += wkk * b2f(v[j]);
  }
  o0 = make_float4(a[0], a[1], a[2], a[3]);
  o1 = make_float4(a[4], a[5], a[6], a[7]);
  *(float4*)op = o0;
  *(float4*)(op + 4) = o1;
}

__global__ __launch_bounds__(256) void k_sentinel(float* o, int n) {
  int i = blockIdx.x * 256 + threadIdx.x;
  if (i < n) o[i] = 12345.0f;
}

extern "C" void kernel_launch(void* const* d_in, const int* in_sizes, int n_in,
                              void* d_out, int out_size, void* d_ws, size_t ws_size,
                              hipStream_t stream) {
  const float* x       = (const float*)d_in[0];
  const float* gate_w  = (const float*)d_in[1];
  const float* gate_b  = (const float*)d_in[2];
  const float* w_gate  = (const float*)d_in[3];
  const float* w_up    = (const float*)d_in[4];
  const float* w_down  = (const float*)d_in[5];
  const float* ws_gate = (const float*)d_in[6];
  const float* ws_up   = (const float*)d_in[7];
  const float* ws_down = (const float*)d_in[8];
  float* out = (float*)d_out;

  char* base = (char*)d_ws;
  char* p = base;
  auto alloc = [&](size_t bytes) -> char* {
    char* r = p;
    p += (bytes + 255) & ~(size_t)255;
    return r;
  };
  // slotA: gate^T then down^T (routed).  slotB: up^T then routed down-output.
  u16* slotA = (u16*)alloc((size_t)NE * ID * HD * 2);            // 92.3 MB
  u16* slotB = (u16*)alloc((size_t)NE * CAPE * HD * 2);          // 100.7 MB
  u16* xb    = (u16*)alloc((size_t)TT * HD * 2);
  u16* gbuf  = (u16*)alloc((size_t)NE * CAPE * ID * 2);          // routed act
  u16* swTg  = (u16*)alloc((size_t)SHD * HD * 2);                // shared gate^T -> down^T
  u16* swTu  = (u16*)alloc((size_t)SHD * HD * 2);                // shared up^T
  u16* sgb   = (u16*)alloc((size_t)TT * SHD * 2);                // shared act
  int*   tidx  = (int*)alloc((size_t)TT * TOPK * 4);
  float* twv   = (float*)alloc((size_t)TT * TOPK * 4);
  int*   ridx  = (int*)alloc((size_t)TT * TOPK * 4);
  int*   torow = (int*)alloc((size_t)NE * CAPE * 4);
  int*   cnts  = (int*)alloc(64);
  int*   ctrs  = (int*)alloc(64);
  u16* wTg = slotA;   // gate^T
  u16* wTu = slotB;   // up^T
  u16* wTd = slotA;   // down^T (gate^T dead after merged pdual)
  u16* dbuf = slotB;  // routed down output (up^T dead after merged pdual)

  if ((size_t)(p - base) > ws_size) {
    k_sentinel<<<dim3((out_size + 255) / 256), dim3(256), 0, stream>>>(out, out_size);
    return;
  }

  dim3 b256(256);

  k_cvt<<<dim3((TT * HD) / (8 * 256)), b256, 0, stream>>>(x, xb);
  k_init<<<dim3(1), dim3(64), 0, stream>>>(ctrs);
  k_gate2<<<dim3(TT / 8), b256, 0, stream>>>(x, gate_w, gate_b, tidx, twv);
  k_count_pos<<<dim3(NE), b256, 0, stream>>>(tidx, ridx, torow, cnts);

  // ---- all gate/up transposes (two merged launches) ----
  k_transpose_cvt2<<<dim3(HD / 64, ID / 64, 2 * NE), b256, 0, stream>>>(
      w_gate, w_up, wTg, wTu, HD, ID, (long)HD * ID, (long)ID * HD, NE);
  k_transpose_cvt2<<<dim3(HD / 64, SHD / 64, 2), b256, 0, stream>>>(
      ws_gate, ws_up, swTg, swTu, HD, SHD, 0, 0, 1);

  // ---- merged pdual: routed job + shared job, one counter ----
  PJob j1{wTg, wTu, gbuf, torow, cnts, 0, ID, CAPE,
          CAPE / 128, ID / 64, NE, (long)ID * HD};
  PJob j2{swTg, swTu, sgb, nullptr, nullptr, TT, SHD, 0,
          TT / 128, SHD / 64, 1, 0};
  k_pdual2<<<dim3(PGRID), b256, 0, stream>>>(xb, HD, HD, j1, j2, ctrs + 0);

  // ---- both down transposes (wTd<-slotA, swTg reuse: both dead after pdual2) ----
  k_transpose_cvt<<<dim3(ID / 64, HD / 64, NE), b256, 0, stream>>>(
      w_down, wTd, ID, HD, (long)ID * HD, (long)HD * ID);
  k_transpose_cvt<<<dim3(SHD / 64, HD / 64, 1), b256, 0, stream>>>(ws_down, swTg, SHD, HD, 0, 0);

  // ---- merged down GEMMs: routed (16 z-slices) + shared (1 z-slice) ----
  DJob d1{gbuf, wTd, dbuf, cnts, 0, ID, ID, HD, CAPE, 0, (long)HD * ID};
  DJob d2{sgb, swTg, out, nullptr, TT, SHD, SHD, HD, 0, 1, 0};
  k_gemm3m<<<dim3(16, HD / 128, NE + 1), b256, 0, stream>>>(d1, d2, NE);

  // ---- combine routed into out ----
  k_combine<<<dim3(TT), b256, 0, stream>>>(dbuf, ridx, twv, out);
}

// Round 17
// 719.778 us; speedup vs baseline: 1.1139x; 1.1139x over previous
//
#include <hip/hip_runtime.h>

typedef unsigned short u16;
typedef u16  u16x8 __attribute__((ext_vector_type(8)));
typedef u16  u16x4 __attribute__((ext_vector_type(4)));
typedef short s16x8 __attribute__((ext_vector_type(8)));
typedef float f32x4 __attribute__((ext_vector_type(4)));

static constexpr int TT   = 2048;   // tokens (B*S)
static constexpr int HD   = 2048;   // hidden
static constexpr int ID   = 1408;   // expert intermediate
static constexpr int NE   = 16;     // experts
static constexpr int TOPK = 6;
static constexpr int CAPE = 1536;   // capacity
static constexpr int SHD  = 2816;   // shared intermediate (2*I)
static constexpr float RSF_ = 2.5f;
static constexpr int PGRID = 1024;  // persistent blocks (256 CU x 4)

struct PJob {               // one dual-GEMM job: act = silu(A*B0^T)*(A*B1^T)
  const u16 *B0, *B1;
  u16* C;
  const int* row_map;
  const int* counts;
  int Mfixed, ldc, row_cap, mtiles, ntiles, nexp;
  long b_stride;
};

__device__ __forceinline__ u16 f2b(float f) {
  unsigned int u = __builtin_bit_cast(unsigned int, f);
  unsigned int r = (u + 0x7FFFu + ((u >> 16) & 1u)) >> 16;
  return (u16)r;
}
__device__ __forceinline__ float b2f(u16 u) {
  unsigned int v = ((unsigned int)u) << 16;
  return __builtin_bit_cast(float, v);
}

__device__ __forceinline__ void gl_lds16(const u16* gp, u16* lp) {
  __builtin_amdgcn_global_load_lds(
      (const __attribute__((address_space(1))) void*)(unsigned long long)(const void*)gp,
      (__attribute__((address_space(3))) void*)(unsigned int)(unsigned long long)(void*)lp,
      16, 0, 0);
}

// sequential tile order for persistent kernels (bx fastest)
__device__ __forceinline__ void seq_map(int idx, int mtiles, int ntiles,
                                        int& bx, int& by, int& e) {
  bx = idx % mtiles;
  int tq = idx / mtiles;
  by = tq % ntiles;
  e  = tq / ntiles;
}

// ---------------- x fp32 -> bf16 ----------------
__global__ __launch_bounds__(256) void k_cvt(const float* __restrict__ in, u16* __restrict__ out) {
  size_t i = (size_t)blockIdx.x * 256 + threadIdx.x;
  const float4* p = (const float4*)in;
  float4 v0 = p[i * 2], v1 = p[i * 2 + 1];
  u16x8 o = { f2b(v0.x), f2b(v0.y), f2b(v0.z), f2b(v0.w),
              f2b(v1.x), f2b(v1.y), f2b(v1.z), f2b(v1.w) };
  *(u16x8*)(out + i * 8) = o;
}

__global__ __launch_bounds__(64) void k_init(int* c) {
  if (threadIdx.x < 16) c[threadIdx.x] = 0;
}

// ---------------- fused gate ----------------
__global__ __launch_bounds__(256) void k_gate2(const float* __restrict__ x,
    const float* __restrict__ gw, const float* __restrict__ gb,
    int* __restrict__ topk_idx, float* __restrict__ topk_w) {
  const int t = threadIdx.x;
  const int tok0 = blockIdx.x * 8;
  const int i  = t >> 5;
  const int sub = t & 31;
  const int e  = sub & 15;
  const int kh = sub >> 4;
  const float4* xr = (const float4*)(x + (size_t)(tok0 + i) * HD) + kh * (HD / 8);
  const float4* wr = (const float4*)(gw + (size_t)e * HD) + kh * (HD / 8);
  float acc = 0.f;
  #pragma unroll 8
  for (int k = 0; k < HD / 8; ++k) {
    float4 a = xr[k], b = wr[k];
    acc += a.x * b.x + a.y * b.y;
    acc += a.z * b.z + a.w * b.w;
  }
  acc += __shfl_down(acc, 16);
  __shared__ float lg[8][16];
  if (sub < 16) lg[i][e] = acc;
  __syncthreads();
  if (t >= 8) return;
  const int tok = tok0 + t;
  float s[NE], sc[NE];
  #pragma unroll
  for (int ee = 0; ee < NE; ++ee) {
    s[ee]  = 1.f / (1.f + expf(-lg[t][ee]));
    sc[ee] = s[ee] + gb[ee];
  }
  float gs[4];
  #pragma unroll
  for (int g = 0; g < 4; ++g) {
    float m1 = -1e30f, m2 = -1e30f;
    #pragma unroll
    for (int j = 0; j < 4; ++j) {
      float v = sc[g * 4 + j];
      if (v > m1) { m2 = m1; m1 = v; } else if (v > m2) m2 = v;
    }
    gs[g] = m1 + m2;
  }
  int g0 = 0;
  #pragma unroll
  for (int g = 1; g < 4; ++g) if (gs[g] > gs[g0]) g0 = g;
  int g1 = -1; float g1v = -1e30f;
  #pragma unroll
  for (int g = 0; g < 4; ++g) {
    if (g == g0) continue;
    if (g1 < 0 || gs[g] > g1v) { g1 = g; g1v = gs[g]; }
  }
  float tmp[NE];
  #pragma unroll
  for (int ee = 0; ee < NE; ++ee) {
    int g = ee >> 2;
    tmp[ee] = (g == g0 || g == g1) ? sc[ee] : 0.0f;
  }
  unsigned used = 0;
  float wsum = 0.f;
  int idxs[TOPK]; float wv[TOPK];
  #pragma unroll
  for (int k = 0; k < TOPK; ++k) {
    int best = -1; float bv = -2e30f;
    #pragma unroll
    for (int ee = 0; ee < NE; ++ee) {
      bool ok = (((used >> ee) & 1u) == 0u) && (tmp[ee] > bv);
      if (ok) { bv = tmp[ee]; best = ee; }
    }
    used |= 1u << best;
    float sv = 0.f;
    #pragma unroll
    for (int ee = 0; ee < NE; ++ee) if (ee == best) sv = s[ee];
    idxs[k] = best; wv[k] = sv; wsum += sv;
  }
  float scale = RSF_ / (wsum + 1e-20f);
  #pragma unroll
  for (int k = 0; k < TOPK; ++k) {
    topk_idx[tok * TOPK + k] = idxs[k];
    topk_w[tok * TOPK + k]   = wv[k] * scale;
  }
}

// ---------------- stable per-expert positions ----------------
__global__ __launch_bounds__(256) void k_count_pos(const int* __restrict__ topk_idx,
    int* __restrict__ rowidx, int* __restrict__ tok_of_row, int* __restrict__ counts) {
  const int e = blockIdx.x, t = threadIdx.x;
  __shared__ int pref[256];
  const int t0 = t * 8;
  int c = 0;
  for (int tt = t0; tt < t0 + 8; ++tt)
    for (int k = 0; k < TOPK; ++k) c += (topk_idx[tt * TOPK + k] == e) ? 1 : 0;
  pref[t] = c;
  __syncthreads();
  for (int off = 1; off < 256; off <<= 1) {
    int v = (t >= off) ? pref[t - off] : 0;
    __syncthreads();
    pref[t] += v;
    __syncthreads();
  }
  int run = pref[t] - c;
  if (t == 255) counts[e] = (pref[255] < CAPE) ? pref[255] : CAPE;
  for (int tt = t0; tt < t0 + 8; ++tt)
    for (int k = 0; k < TOPK; ++k)
      if (topk_idx[tt * TOPK + k] == e) {
        if (run < CAPE) {
          rowidx[tt * TOPK + k] = e * CAPE + run;
          tok_of_row[e * CAPE + run] = tt;
        } else {
          rowidx[tt * TOPK + k] = -1;
        }
        ++run;
      }
}

// ---------------- transpose + convert: fp32 [R][C] -> bf16 [C][R] ----------------
__global__ __launch_bounds__(256) void k_transpose_cvt(const float* __restrict__ in,
    u16* __restrict__ out, int R, int Cc, long zin, long zout) {
  __shared__ float tile[64][65];
  const float* src = in + (size_t)blockIdx.z * zin;
  u16* dst = out + (size_t)blockIdx.z * zout;
  const int r0 = blockIdx.x * 64, c0 = blockIdx.y * 64, t = threadIdx.x;
  #pragma unroll
  for (int i = 0; i < 4; ++i) {
    int c = t + 256 * i;
    int r = c >> 4, cg = (c & 15) << 2;
    float4 v = *(const float4*)(src + (size_t)(r0 + r) * Cc + c0 + cg);
    tile[r][cg + 0] = v.x; tile[r][cg + 1] = v.y;
    tile[r][cg + 2] = v.z; tile[r][cg + 3] = v.w;
  }
  __syncthreads();
  #pragma unroll
  for (int i = 0; i < 4; ++i) {
    int c = t + 256 * i;
    int oc = c >> 4, og = (c & 15) << 2;
    u16x4 w;
    #pragma unroll
    for (int j = 0; j < 4; ++j) w[j] = f2b(tile[og + j][oc]);
    *(u16x4*)(dst + (size_t)(c0 + oc) * R + r0 + og) = w;
  }
}

// ---- paired transpose: two same-shape matrices in one launch (z split) ----
__global__ __launch_bounds__(256) void k_transpose_cvt2(
    const float* __restrict__ in0, const float* __restrict__ in1,
    u16* __restrict__ out0, u16* __restrict__ out1,
    int R, int Cc, long zin, long zout, int nz) {
  __shared__ float tile[64][65];
  const int zi = blockIdx.z;
  const int mat = (zi >= nz) ? 1 : 0;
  const int zz  = mat ? zi - nz : zi;
  const float* src = (mat ? in1 : in0) + (size_t)zz * zin;
  u16* dst = (mat ? out1 : out0) + (size_t)zz * zout;
  const int r0 = blockIdx.x * 64, c0 = blockIdx.y * 64, t = threadIdx.x;
  #pragma unroll
  for (int i = 0; i < 4; ++i) {
    int c = t + 256 * i;
    int r = c >> 4, cg = (c & 15) << 2;
    float4 v = *(const float4*)(src + (size_t)(r0 + r) * Cc + c0 + cg);
    tile[r][cg + 0] = v.x; tile[r][cg + 1] = v.y;
    tile[r][cg + 2] = v.z; tile[r][cg + 3] = v.w;
  }
  __syncthreads();
  #pragma unroll
  for (int i = 0; i < 4; ++i) {
    int c = t + 256 * i;
    int oc = c >> 4, og = (c & 15) << 2;
    u16x4 w;
    #pragma unroll
    for (int j = 0; j < 4; ++j) w[j] = f2b(tile[og + j][oc]);
    *(u16x4*)(dst + (size_t)(c0 + oc) * R + r0 + og) = w;
  }
}

// ====== merged persistent dual GEMM (2 jobs, one counter) ======
// Per tile: act = silu(A*B0^T) * (A*B1^T), BM=128 BN=64; K uniform (=HD).
__global__ __launch_bounds__(256, 4) void k_pdual2(
    const u16* __restrict__ A, int K, int lda,
    PJob j1, PJob j2, int* __restrict__ counter) {
  const int t = threadIdx.x;
  const int l = t & 63, w = t >> 6;
  const int wm = (w >> 1) * 64, wn = (w & 1) * 32;
  const int l15 = l & 15, g0 = l >> 4;

  __shared__ __align__(16) u16 As[2][128 * 32];
  __shared__ __align__(16) u16 B0s[2][64 * 32];
  __shared__ __align__(16) u16 B1s[2][64 * 32];
  __shared__ int s_tile;

  int aoff[4], boff[2];
  #pragma unroll
  for (int i = 0; i < 4; ++i) {
    int rA = wm + i * 16 + l15;
    aoff[i] = rA * 64 + ((g0 ^ ((rA >> 1) & 3)) << 4);
  }
  #pragma unroll
  for (int i = 0; i < 2; ++i) {
    int rB = wn + i * 16 + l15;
    boff[i] = rB * 64 + ((g0 ^ ((rB >> 1) & 3)) << 4);
  }

  const int ntot1 = j1.mtiles * j1.ntiles * j1.nexp;
  const int ntot2 = j2.mtiles * j2.ntiles * j2.nexp;
  const int ntot  = ntot1 + ntot2;
  const int nk = K >> 5;
  const int cl = l15, rw = g0 * 4;

  for (;;) {
    if (t == 0) s_tile = atomicAdd(counter, 1);
    __syncthreads();
    int idx = s_tile;
    __syncthreads();
    if (idx >= ntot) break;
    const PJob& J = (idx < ntot1) ? j1 : j2;
    int ii = (idx < ntot1) ? idx : idx - ntot1;
    int bx, by, e;
    seq_map(ii, J.mtiles, J.ntiles, bx, by, e);
    const int cnt = J.counts ? J.counts[e] : J.Mfixed;
    const int M_e = J.counts ? (cnt < J.row_cap ? cnt : J.row_cap) : J.Mfixed;
    const int m0 = bx * 128;
    if (m0 >= M_e) continue;
    const int n0 = by * 64;
    const int row_base = J.counts ? e * J.row_cap : 0;
    const u16* B0e = J.B0 + (size_t)e * J.b_stride;
    const u16* B1e = J.B1 + (size_t)e * J.b_stride;

    const u16 *ap[2], *b0p, *b1p;
    int loffA[2], loffB;
    #pragma unroll
    for (int i = 0; i < 2; ++i) {
      int c = t + 256 * i;
      int row = c >> 2, g = c & 3;
      int kg = g ^ ((row >> 1) & 3);
      loffA[i] = c * 8;
      int rg = m0 + row; if (rg > M_e - 1) rg = M_e - 1;
      int arow = J.row_map ? J.row_map[row_base + rg] : row_base + rg;
      ap[i] = A + (size_t)arow * lda + kg * 8;
    }
    {
      int row = t >> 2, g = t & 3;
      int kg = g ^ ((row >> 1) & 3);
      loffB = t * 8;
      b0p = B0e + (size_t)(n0 + row) * K + kg * 8;
      b1p = B1e + (size_t)(n0 + row) * K + kg * 8;
    }

    f32x4 accg[4][2], accu[4][2];
    #pragma unroll
    for (int m = 0; m < 4; ++m)
      #pragma unroll
      for (int n = 0; n < 2; ++n) { accg[m][n] = f32x4{0,0,0,0}; accu[m][n] = f32x4{0,0,0,0}; }

    #pragma unroll
    for (int i = 0; i < 2; ++i) { gl_lds16(ap[i], &As[0][loffA[i]]); ap[i] += 32; }
    gl_lds16(b0p, &B0s[0][loffB]); b0p += 32;
    gl_lds16(b1p, &B1s[0][loffB]); b1p += 32;
    __syncthreads();
    int cur = 0;
    for (int ks = 0; ks < nk; ++ks) {
      if (ks + 1 < nk) {
        #pragma unroll
        for (int i = 0; i < 2; ++i) { gl_lds16(ap[i], &As[cur ^ 1][loffA[i]]); ap[i] += 32; }
        gl_lds16(b0p, &B0s[cur ^ 1][loffB]); b0p += 32;
        gl_lds16(b1p, &B1s[cur ^ 1][loffB]); b1p += 32;
      }
      s16x8 af[4], bf0[2], bf1[2];
      #pragma unroll
      for (int i = 0; i < 4; ++i)
        af[i] = __builtin_bit_cast(s16x8, *(const u16x8*)((const char*)As[cur] + aoff[i]));
      #pragma unroll
      for (int i = 0; i < 2; ++i) {
        bf0[i] = __builtin_bit_cast(s16x8, *(const u16x8*)((const char*)B0s[cur] + boff[i]));
        bf1[i] = __builtin_bit_cast(s16x8, *(const u16x8*)((const char*)B1s[cur] + boff[i]));
      }
      #pragma unroll
      for (int m = 0; m < 4; ++m)
        #pragma unroll
        for (int n = 0; n < 2; ++n) {
          accg[m][n] = __builtin_amdgcn_mfma_f32_16x16x32_bf16(af[m], bf0[n], accg[m][n], 0, 0, 0);
          accu[m][n] = __builtin_amdgcn_mfma_f32_16x16x32_bf16(af[m], bf1[n], accu[m][n], 0, 0, 0);
        }
      __syncthreads();
      cur ^= 1;
    }

    #pragma unroll
    for (int m = 0; m < 4; ++m) {
      #pragma unroll
      for (int n = 0; n < 2; ++n) {
        f32x4 vg = accg[m][n], vu = accu[m][n];
        int gr0 = m0 + wm + m * 16 + rw;
        int gc  = n0 + wn + n * 16 + cl;
        #pragma unroll
        for (int j = 0; j < 4; ++j) {
          int rr = gr0 + j;
          if (rr < M_e) {
            float gf = vg[j];
            float act = gf / (1.f + __expf(-gf)) * vu[j];
            J.C[(size_t)(row_base + rr) * J.ldc + gc] = f2b(act);
          }
        }
      }
    }
  }
}

// ====== single GEMM (round-5 config): BM=BN=128, BK=64, 2-buffer, XCD swizzle ======
// EPI: 0 = store bf16; 1 = store fp32.
template <int EPI>
__global__ __launch_bounds__(256) void k_gemm3(
    const u16* __restrict__ A, const u16* __restrict__ Bt, void* __restrict__ Cptr,
    const int* __restrict__ counts, int Mfixed, int K, int lda, int ldc,
    long b_stride, int row_cap) {
  unsigned gx = gridDim.x, gy = gridDim.y, gz = gridDim.z;
  unsigned F = (blockIdx.z * gy + blockIdx.y) * gx + blockIdx.x;
  unsigned Nn = gx * gy * gz;
  unsigned q = Nn >> 3, r = Nn & 7;
  unsigned xcd = F & 7, pos = F >> 3;
  unsigned wi = (xcd < r) ? xcd * (q + 1) + pos
                          : r * (q + 1) + (xcd - r) * q + pos;
  unsigned bx = wi % gx, tq = wi / gx;
  unsigned by = tq % gy, bz = tq / gy;

  const int e = bz;
  const int cnt = counts ? counts[e] : Mfixed;
  const int M_e = counts ? (cnt < row_cap ? cnt : row_cap) : Mfixed;
  const int m0 = bx * 128;
  if (m0 >= M_e) return;
  const int n0 = by * 128;
  const int row_base = counts ? e * row_cap : 0;
  const u16* Bte = Bt + (size_t)e * b_stride;

  __shared__ __align__(16) u16 As[2][128 * 64];   // 16 KB x2
  __shared__ __align__(16) u16 Bs[2][128 * 64];   // 16 KB x2

  const int t = threadIdx.x;
  const int l = t & 63, w = t >> 6;
  const int wm = (w >> 1) * 64, wn = (w & 1) * 64;

  const u16 *ap[4], *bp[4];
  int loff[4];
  #pragma unroll
  for (int i = 0; i < 4; ++i) {
    int c = t + 256 * i;
    int row = c >> 3, pphys = c & 7;
    int kc = pphys ^ (row & 7);
    loff[i] = c * 8;
    int rg = m0 + row; if (rg > M_e - 1) rg = M_e - 1;
    ap[i] = A + (size_t)(row_base + rg) * lda + kc * 8;
    bp[i] = Bte + (size_t)(n0 + row) * K + kc * 8;
  }

  f32x4 acc[4][4];
  #pragma unroll
  for (int m = 0; m < 4; ++m)
    #pragma unroll
    for (int n = 0; n < 4; ++n) acc[m][n] = f32x4{0, 0, 0, 0};

  const int l15 = l & 15, g0 = l >> 4;
  int aoff[2][4], boff[2][4];
  #pragma unroll
  for (int s = 0; s < 2; ++s)
    #pragma unroll
    for (int i = 0; i < 4; ++i) {
      int rA = wm + i * 16 + l15;
      int rB = wn + i * 16 + l15;
      aoff[s][i] = rA * 128 + ((((s << 2) | g0) ^ (rA & 7)) << 4);
      boff[s][i] = rB * 128 + ((((s << 2) | g0) ^ (rB & 7)) << 4);
    }

  const int nk = K >> 6;
  #pragma unroll
  for (int i = 0; i < 4; ++i) {
    gl_lds16(ap[i], &As[0][loff[i]]); ap[i] += 64;
    gl_lds16(bp[i], &Bs[0][loff[i]]); bp[i] += 64;
  }
  __syncthreads();
  int cur = 0;
  for (int ks = 0; ks < nk; ++ks) {
    if (ks + 1 < nk) {
      #pragma unroll
      for (int i = 0; i < 4; ++i) {
        gl_lds16(ap[i], &As[cur ^ 1][loff[i]]); ap[i] += 64;
        gl_lds16(bp[i], &Bs[cur ^ 1][loff[i]]); bp[i] += 64;
      }
    }
    #pragma unroll
    for (int s = 0; s < 2; ++s) {
      s16x8 af[4], bfr[4];
      #pragma unroll
      for (int i = 0; i < 4; ++i) {
        af[i]  = __builtin_bit_cast(s16x8, *(const u16x8*)((const char*)As[cur] + aoff[s][i]));
        bfr[i] = __builtin_bit_cast(s16x8, *(const u16x8*)((const char*)Bs[cur] + boff[s][i]));
      }
      #pragma unroll
      for (int m = 0; m < 4; ++m)
        #pragma unroll
        for (int n = 0; n < 4; ++n)
          acc[m][n] = __builtin_amdgcn_mfma_f32_16x16x32_bf16(af[m], bfr[n], acc[m][n], 0, 0, 0);
    }
    __syncthreads();
    cur ^= 1;
  }

  const int cl = l15, rw = g0 * 4;
  #pragma unroll
  for (int m = 0; m < 4; ++m) {
    #pragma unroll
    for (int n = 0; n < 4; ++n) {
      f32x4 v = acc[m][n];
      int gr0 = m0 + wm + m * 16 + rw;
      int gc  = n0 + wn + n * 16 + cl;
      #pragma unroll
      for (int j = 0; j < 4; ++j) {
        int rr = gr0 + j;
        if (rr < M_e) {
          size_t ci = (size_t)(row_base + rr) * ldc + gc;
          if (EPI == 1) ((float*)Cptr)[ci] = v[j];
          else          ((u16*)Cptr)[ci]   = f2b(v[j]);
        }
      }
    }
  }
}

// ---------------- combine ----------------
__global__ __launch_bounds__(256) void k_combine(const u16* __restrict__ down,
    const int* __restrict__ rowidx, const float* __restrict__ tw,
    float* __restrict__ out) {
  const int t = blockIdx.x, l = threadIdx.x;
  __shared__ int rid[TOPK];
  __shared__ float wk[TOPK];
  if (l < TOPK) { rid[l] = rowidx[t * TOPK + l]; wk[l] = tw[t * TOPK + l]; }
  __syncthreads();
  const int h0 = l * 8;
  float* op = out + (size_t)t * HD + h0;
  float4 o0 = *(float4*)op, o1 = *(float4*)(op + 4);
  float a[8] = { o0.x, o0.y, o0.z, o0.w, o1.x, o1.y, o1.z, o1.w };
  #pragma unroll
  for (int k = 0; k < TOPK; ++k) {
    int r = rid[k];
    if (r < 0) continue;
    float wkk = wk[k];
    u16x8 v = *(const u16x8*)(down + (size_t)r * HD + h0);
    #pragma unroll
    for (int j = 0; j < 8; ++j) a[j] += wkk * b2f(v[j]);
  }
  o0 = make_float4(a[0], a[1], a[2], a[3]);
  o1 = make_float4(a[4], a[5], a[6], a[7]);
  *(float4*)op = o0;
  *(float4*)(op + 4) = o1;
}

__global__ __launch_bounds__(256) void k_sentinel(float* o, int n) {
  int i = blockIdx.x * 256 + threadIdx.x;
  if (i < n) o[i] = 12345.0f;
}

extern "C" void kernel_launch(void* const* d_in, const int* in_sizes, int n_in,
                              void* d_out, int out_size, void* d_ws, size_t ws_size,
                              hipStream_t stream) {
  const float* x       = (const float*)d_in[0];
  const float* gate_w  = (const float*)d_in[1];
  const float* gate_b  = (const float*)d_in[2];
  const float* w_gate  = (const float*)d_in[3];
  const float* w_up    = (const float*)d_in[4];
  const float* w_down  = (const float*)d_in[5];
  const float* ws_gate = (const float*)d_in[6];
  const float* ws_up   = (const float*)d_in[7];
  const float* ws_down = (const float*)d_in[8];
  float* out = (float*)d_out;

  char* base = (char*)d_ws;
  char* p = base;
  auto alloc = [&](size_t bytes) -> char* {
    char* r = p;
    p += (bytes + 255) & ~(size_t)255;
    return r;
  };
  // slotA: gate^T then down^T (routed).  slotB: up^T then routed down-output.
  u16* slotA = (u16*)alloc((size_t)NE * ID * HD * 2);            // 92.3 MB
  u16* slotB = (u16*)alloc((size_t)NE * CAPE * HD * 2);          // 100.7 MB
  u16* xb    = (u16*)alloc((size_t)TT * HD * 2);
  u16* gbuf  = (u16*)alloc((size_t)NE * CAPE * ID * 2);          // routed act
  u16* swTg  = (u16*)alloc((size_t)SHD * HD * 2);                // shared gate^T -> down^T
  u16* swTu  = (u16*)alloc((size_t)SHD * HD * 2);                // shared up^T
  u16* sgb   = (u16*)alloc((size_t)TT * SHD * 2);                // shared act
  int*   tidx  = (int*)alloc((size_t)TT * TOPK * 4);
  float* twv   = (float*)alloc((size_t)TT * TOPK * 4);
  int*   ridx  = (int*)alloc((size_t)TT * TOPK * 4);
  int*   torow = (int*)alloc((size_t)NE * CAPE * 4);
  int*   cnts  = (int*)alloc(64);
  int*   ctrs  = (int*)alloc(64);
  u16* wTg = slotA;   // gate^T
  u16* wTu = slotB;   // up^T
  u16* wTd = slotA;   // down^T (gate^T dead after merged pdual)
  u16* dbuf = slotB;  // routed down output (up^T dead after merged pdual)

  if ((size_t)(p - base) > ws_size) {
    k_sentinel<<<dim3((out_size + 255) / 256), dim3(256), 0, stream>>>(out, out_size);
    return;
  }

  dim3 b256(256);

  k_cvt<<<dim3((TT * HD) / (8 * 256)), b256, 0, stream>>>(x, xb);
  k_init<<<dim3(1), dim3(64), 0, stream>>>(ctrs);
  k_gate2<<<dim3(TT / 8), b256, 0, stream>>>(x, gate_w, gate_b, tidx, twv);
  k_count_pos<<<dim3(NE), b256, 0, stream>>>(tidx, ridx, torow, cnts);

  // ---- all gate/up transposes (two merged launches) ----
  k_transpose_cvt2<<<dim3(HD / 64, ID / 64, 2 * NE), b256, 0, stream>>>(
      w_gate, w_up, wTg, wTu, HD, ID, (long)HD * ID, (long)ID * HD, NE);
  k_transpose_cvt2<<<dim3(HD / 64, SHD / 64, 2), b256, 0, stream>>>(
      ws_gate, ws_up, swTg, swTu, HD, SHD, 0, 0, 1);

  // ---- merged pdual: routed job + shared job, one counter ----
  PJob j1{wTg, wTu, gbuf, torow, cnts, 0, ID, CAPE,
          CAPE / 128, ID / 64, NE, (long)ID * HD};
  PJob j2{swTg, swTu, sgb, nullptr, nullptr, TT, SHD, 0,
          TT / 128, SHD / 64, 1, 0};
  k_pdual2<<<dim3(PGRID), b256, 0, stream>>>(xb, HD, HD, j1, j2, ctrs + 0);

  // ---- down transposes + down GEMMs ----
  k_transpose_cvt<<<dim3(ID / 64, HD / 64, NE), b256, 0, stream>>>(
      w_down, wTd, ID, HD, (long)ID * HD, (long)HD * ID);
  k_gemm3<0><<<dim3(CAPE / 128, HD / 128, NE), b256, 0, stream>>>(
      gbuf, wTd, dbuf, cnts, 0, ID, ID, HD, (long)HD * ID, CAPE);
  k_transpose_cvt<<<dim3(SHD / 64, HD / 64, 1), b256, 0, stream>>>(ws_down, swTg, SHD, HD, 0, 0);
  k_gemm3<1><<<dim3(TT / 128, HD / 128, 1), b256, 0, stream>>>(
      sgb, swTg, out, nullptr, TT, SHD, SHD, HD, 0, 0);

  // ---- combine routed into out ----
  k_combine<<<dim3(TT), b256, 0, stream>>>(dbuf, ridx, twv, out);
}